// Round 4
// baseline (1411.791 us; speedup 1.0000x reference)
//
#include <hip/hip_runtime.h>
#include <math.h>

// ---------------- problem constants ----------------
#define NN 50000      // nodes
#define NE 150000     // edges
#define NG 2000       // graphs
#define NL 4          // layers
#define AVG_DEG_LOG 1.1308269950720915f

typedef __attribute__((ext_vector_type(8))) short bf8_t;
typedef __attribute__((ext_vector_type(4))) float f4_t;

__device__ inline unsigned short f2bf(float x) {
  union { float f; unsigned int u; } v; v.f = x;
  unsigned int r = (v.u + 0x7FFFu + ((v.u >> 16) & 1u)) >> 16;
  return (unsigned short)r;
}
__device__ inline float bflo(unsigned int u) { union { unsigned int u; float f; } v; v.u = u << 16; return v.f; }
__device__ inline float bfhi(unsigned int u) { union { unsigned int u; float f; } v; v.u = u & 0xFFFF0000u; return v.f; }

// ---------------- preprocessing ----------------
__global__ void k_deg(const int* __restrict__ dst, int* __restrict__ deg) {
  int e = blockIdx.x * 256 + threadIdx.x;
  if (e < NE) atomicAdd(&deg[dst[e]], 1);
}

__global__ __launch_bounds__(1024) void k_scan(const int* __restrict__ deg, int* __restrict__ off) {
  __shared__ int wsum[16];
  __shared__ int wpre[16];
  __shared__ int carry_s;
  int tid = threadIdx.x, lane = tid & 63, wv = tid >> 6;
  if (tid == 0) carry_s = 0;
  __syncthreads();
  for (int base = 0; base < NN; base += 1024) {
    int i = base + tid;
    int v = (i < NN) ? deg[i] : 0;
    int incl = v;
    #pragma unroll
    for (int d = 1; d < 64; d <<= 1) { int t = __shfl_up(incl, d); if (lane >= d) incl += t; }
    if (lane == 63) wsum[wv] = incl;
    __syncthreads();
    if (wv == 0) {
      int s = (lane < 16) ? wsum[lane] : 0;
      int sc = s;
      #pragma unroll
      for (int d = 1; d < 16; d <<= 1) { int t = __shfl_up(sc, d); if (lane >= d) sc += t; }
      if (lane < 16) wpre[lane] = sc - s;
    }
    __syncthreads();
    int carry = carry_s;
    int excl = carry + wpre[wv] + incl - v;
    if (i < NN) off[i] = excl;
    __syncthreads();
    if (tid == 1023) carry_s = excl + v;
    __syncthreads();
  }
  if (tid == 0) off[NN] = carry_s;
}

__global__ void k_amp(const int* __restrict__ deg, const int* __restrict__ off,
                      float* __restrict__ amp, float* __restrict__ invamp, int* __restrict__ cursor) {
  int n = blockIdx.x * 256 + threadIdx.x;
  if (n < NN) {
    int d = deg[n]; if (d < 1) d = 1;
    float a = logf((float)d + 1.0f) / AVG_DEG_LOG;
    amp[n] = a; invamp[n] = 1.0f / a;
    cursor[n] = off[n];
  }
}

// pack src (16 bit) | attr (<<16) into one u32 per CSR slot
__global__ void k_fill(const int* __restrict__ src, const int* __restrict__ dst,
                       const int* __restrict__ attr, int* __restrict__ cursor,
                       unsigned int* __restrict__ cpack) {
  int e = blockIdx.x * 256 + threadIdx.x;
  if (e < NE) {
    int d = dst[e];
    int p = atomicAdd(&cursor[d], 1);
    cpack[p] = (unsigned int)src[e] | ((unsigned int)attr[e] << 16);
  }
}

// node embedding -> hbf [NN,96] bf16 (cols 75..95 zero)
__global__ void k_embed(const int* __restrict__ x, const float* __restrict__ emb, unsigned short* __restrict__ hbf) {
  int i = blockIdx.x * 256 + threadIdx.x;
  if (i < NN * 96) {
    int n = i / 96, c = i - (i / 96) * 96;
    hbf[i] = (c < 75) ? f2bf(emb[x[n] * 75 + c]) : (unsigned short)0;
  }
}

// ---------------- weight prep ----------------
__global__ void k_wxlin(const float* __restrict__ Wpost, const float* __restrict__ Wlin, float* __restrict__ WXlin) {
  int l = blockIdx.x;
  for (int idx = threadIdx.x; idx < 5625; idx += 256) {
    int k = idx / 75, j = idx - (idx / 75) * 75;
    float s = 0.0f;
    for (int o = 0; o < 75; ++o) {
      int t = o / 15, jj = o - t * 15;
      s += Wpost[((l * 5 + t) * 975 + k) * 15 + jj] * Wlin[l * 5625 + o * 75 + j];
    }
    WXlin[l * 5625 + idx] = s;
  }
}

__global__ void k_zb(const float* __restrict__ bpost, const float* __restrict__ blin,
                     const float* __restrict__ Wlin, float* __restrict__ zb) {
  int l = blockIdx.x, j = threadIdx.x;
  if (j < 75) {
    float s = blin[l * 75 + j];
    for (int o = 0; o < 75; ++o) s += bpost[l * 75 + o] * Wlin[l * 5625 + o * 75 + j];
    zb[l * 75 + j] = s;
  }
}

// one kernel packs: B1Ts [4][384][96] (src block), B1Td [4][384][96] (dst block),
// WXT [4][80][96] (WXlin^T), WlinT [4][80][96] (Wlin^T)
__global__ void k_packAll(const float* __restrict__ Wpre, const float* __restrict__ WXlin,
                          const float* __restrict__ Wlin,
                          unsigned short* __restrict__ B1Ts, unsigned short* __restrict__ B1Td,
                          unsigned short* __restrict__ WXT, unsigned short* __restrict__ WlinT) {
  const int S1 = 4 * 384 * 96;           // B1Ts
  const int S2 = S1 + 4 * 384 * 96;      // B1Td
  const int S3 = S2 + 4 * 80 * 96;       // WXT
  const int S4 = S3 + 4 * 80 * 96;       // WlinT
  int idx = blockIdx.x * 256 + threadIdx.x;
  if (idx < S1) {
    int l = idx / (384 * 96); int rem = idx - l * (384 * 96);
    int c = rem / 96, k = rem - (rem / 96) * 96;
    float v = 0.0f;
    if (c < 375 && k < 75) {
      int t = c / 75, f = c - t * 75;
      v = Wpre[((l * 5 + t) * 225 + 75 + k) * 75 + f];
    }
    B1Ts[idx] = f2bf(v);
  } else if (idx < S2) {
    int m = idx - S1;
    int l = m / (384 * 96); int rem = m - l * (384 * 96);
    int c = rem / 96, k = rem - (rem / 96) * 96;
    float v = 0.0f;
    if (c < 375 && k < 75) {
      int t = c / 75, f = c - t * 75;
      v = Wpre[((l * 5 + t) * 225 + k) * 75 + f];
    }
    B1Td[m] = f2bf(v);
  } else if (idx < S3) {
    int m = idx - S2;
    int l = m / (80 * 96); int rem = m - l * (80 * 96);
    int j = rem / 96, k = rem - (rem / 96) * 96;
    float v = (j < 75 && k < 75) ? WXlin[l * 5625 + k * 75 + j] : 0.0f;
    WXT[m] = f2bf(v);
  } else if (idx < S4) {
    int m = idx - S3;
    int l = m / (80 * 96); int rem = m - l * (80 * 96);
    int j = rem / 96, k = rem - (rem / 96) * 96;
    float v = (j < 75 && k < 75) ? Wlin[l * 5625 + k * 75 + j] : 0.0f;
    WlinT[m] = f2bf(v);
  }
}

// WcombT bf16 [4][5][48][320]: row j=s*15+jj (45 real), col k INTERLEAVED: k = f*4 + agg  (k<300 real)
__global__ void k_packWcomb(const float* __restrict__ Wpost, unsigned short* __restrict__ WcombT) {
  int idx = blockIdx.x * 256 + threadIdx.x;
  if (idx >= 4 * 5 * 48 * 320) return;
  int l = idx / (5 * 48 * 320); int rem = idx - l * (5 * 48 * 320);
  int t = rem / (48 * 320); rem -= t * (48 * 320);
  int j = rem / 320, k = rem - (rem / 320) * 320;
  float v = 0.0f;
  if (j < 45 && k < 300) {
    int s = j / 15, jj = j - s * 15;
    int f = k >> 2, agg = k & 3;
    v = Wpost[((l * 5 + t) * 975 + 75 + s * 300 + agg * 75 + f) * 15 + jj];
  }
  WcombT[idx] = f2bf(v);
}

// etab f32 [4][4][384], pads zero
__global__ void k_etab(const float* __restrict__ edge_emb, const float* __restrict__ We,
                       const float* __restrict__ be, const float* __restrict__ Wpre,
                       float* __restrict__ etab) {
  __shared__ float ev[75];
  int l = blockIdx.x >> 2, a = blockIdx.x & 3;
  int tid = threadIdx.x;
  if (tid < 75) {
    float acc = be[l * 75 + tid];
    for (int k = 0; k < 50; ++k) acc += edge_emb[a * 50 + k] * We[(l * 50 + k) * 75 + tid];
    ev[tid] = acc;
  }
  __syncthreads();
  for (int tf = tid; tf < 384; tf += 256) {
    float acc = 0.0f;
    if (tf < 375) {
      int t = tf / 75, f = tf - t * 75;
      for (int d = 0; d < 75; ++d) acc += ev[d] * Wpre[((l * 5 + t) * 225 + 150 + d) * 75 + f];
    }
    etab[(l * 4 + a) * 384 + tf] = acc;
  }
}

// ---------------- GEMM1 (MFMA): Hsrc only. [NN,96]bf16 @ [96,384]bf16 -> Hsrc bf16 ----------------
__global__ __launch_bounds__(256) void k_gemm1(const unsigned short* __restrict__ hbf,
                                               const unsigned short* __restrict__ B1Ts_l,
                                               unsigned short* __restrict__ Hsrc) {
  int w = threadIdx.x >> 6, lane = threadIdx.x & 63;
  int l15 = lane & 15, l4 = lane >> 4;
  int m0 = blockIdx.x * 64 + w * 16;
  int mA = m0 + l15; if (mA >= NN) mA = NN - 1;
  const unsigned short* ha = hbf + (size_t)mA * 96 + l4 * 8;
  bf8_t a0 = *(const bf8_t*)(ha);
  bf8_t a1 = *(const bf8_t*)(ha + 32);
  bf8_t a2 = *(const bf8_t*)(ha + 64);
  for (int nf = 0; nf < 24; ++nf) {
    int c = nf * 16 + l15;
    const unsigned short* bp = B1Ts_l + (size_t)c * 96 + l4 * 8;
    f4_t acc = {0.f, 0.f, 0.f, 0.f};
    acc = __builtin_amdgcn_mfma_f32_16x16x32_bf16(a0, *(const bf8_t*)(bp), acc, 0, 0, 0);
    acc = __builtin_amdgcn_mfma_f32_16x16x32_bf16(a1, *(const bf8_t*)(bp + 32), acc, 0, 0, 0);
    acc = __builtin_amdgcn_mfma_f32_16x16x32_bf16(a2, *(const bf8_t*)(bp + 64), acc, 0, 0, 0);
    #pragma unroll
    for (int i = 0; i < 4; ++i) {
      int m = m0 + l4 * 4 + i;
      if (m < NN) Hsrc[(size_t)m * 384 + c] = f2bf(acc[i]);
    }
  }
}

// ---------------- fused: prologue MFMA (Cd,Xp) + gather + per-tower MFMA + combine + lin ----------------
// 8 nodes / block, 512 threads (8 waves), one node per wave in gather.
// A layout (bf16): [node][t*320 + f*4 + agg], agg = {mean,min,max,std}; k pads [300,320) zeroed.
__global__ __launch_bounds__(512, 4) void k_agg(
    const unsigned short* __restrict__ hbf,
    const unsigned short* __restrict__ Hsrc,
    const int* __restrict__ off,
    const unsigned int* __restrict__ cpack,
    const float* __restrict__ etab_l,
    const unsigned short* __restrict__ B1Td_l,
    const float* __restrict__ bpre_l,
    const unsigned short* __restrict__ WXT_l,
    const unsigned short* __restrict__ WcombT_l,
    const unsigned short* __restrict__ WlinT_l,
    const float* __restrict__ amp,
    const float* __restrict__ invamp,
    const float* __restrict__ zb_l,
    float* __restrict__ Z) {
  __shared__ __align__(16) unsigned short A_s[8 * 1608];  // 25728 B; later aliased Out f32[8][256] + Cb bf16[8][104]
  __shared__ __align__(16) float Cd_s[8 * 384];
  __shared__ __align__(16) float Xp_s[8 * 80];
  __shared__ __align__(16) float et_s[4 * 384];
  int tid = threadIdx.x;
  int w = tid >> 6, lane = tid & 63;
  int l15 = lane & 15, l4 = lane >> 4;
  int n0 = blockIdx.x * 8;

  // stage etab + zero A_s k-pads
  for (int i = tid; i < 1536; i += 512) et_s[i] = etab_l[i];
  for (int idx = tid; idx < 400; idx += 512) {
    int n = idx / 50; int r = idx - n * 50; int t = r / 10; int j = r - t * 10;
    *((unsigned int*)&A_s[n * 1608 + t * 320 + 300] + j) = 0u;
  }

  // ---- prologue MFMA: Cd_s = hbf_blk @ B1Td + bpre; Xp_s = hbf_blk @ WXT ----
  {
    int arow = n0 + (l15 & 7);
    const unsigned short* ha = hbf + (size_t)arow * 96 + l4 * 8;
    bf8_t pa0 = *(const bf8_t*)(ha);
    bf8_t pa1 = *(const bf8_t*)(ha + 32);
    bf8_t pa2 = *(const bf8_t*)(ha + 64);
    #pragma unroll
    for (int r = 0; r < 3; ++r) {
      int c = (w + r * 8) * 16 + l15;   // 0..383
      const unsigned short* bp = B1Td_l + (size_t)c * 96 + l4 * 8;
      f4_t acc = {0.f, 0.f, 0.f, 0.f};
      acc = __builtin_amdgcn_mfma_f32_16x16x32_bf16(pa0, *(const bf8_t*)(bp), acc, 0, 0, 0);
      acc = __builtin_amdgcn_mfma_f32_16x16x32_bf16(pa1, *(const bf8_t*)(bp + 32), acc, 0, 0, 0);
      acc = __builtin_amdgcn_mfma_f32_16x16x32_bf16(pa2, *(const bf8_t*)(bp + 64), acc, 0, 0, 0);
      float bb = (c < 375) ? bpre_l[c] : 0.0f;
      #pragma unroll
      for (int i = 0; i < 4; ++i) {
        int row = l4 * 4 + i;
        if (row < 8) Cd_s[row * 384 + c] = acc[i] + bb;
      }
    }
    if (w < 5) {
      int c = w * 16 + l15;             // 0..79
      const unsigned short* bp = WXT_l + (size_t)c * 96 + l4 * 8;
      f4_t acc = {0.f, 0.f, 0.f, 0.f};
      acc = __builtin_amdgcn_mfma_f32_16x16x32_bf16(pa0, *(const bf8_t*)(bp), acc, 0, 0, 0);
      acc = __builtin_amdgcn_mfma_f32_16x16x32_bf16(pa1, *(const bf8_t*)(bp + 32), acc, 0, 0, 0);
      acc = __builtin_amdgcn_mfma_f32_16x16x32_bf16(pa2, *(const bf8_t*)(bp + 64), acc, 0, 0, 0);
      #pragma unroll
      for (int i = 0; i < 4; ++i) {
        int row = l4 * 4 + i;
        if (row < 8) Xp_s[row * 80 + c] = acc[i];
      }
    }
  }
  __syncthreads();

  // ---- gather: one node per wave, lane owns 8 channels, edge loop unrolled x4 ----
  {
    int g = n0 + w;
    int e0 = off[g], e1 = off[g + 1];
    if (lane < 47) {
      int c0 = lane * 8;
      float s8[8], q8[8], mn8[8], mx8[8];
      #pragma unroll
      for (int j = 0; j < 8; ++j) {
        s8[j] = 0.0f; q8[j] = 0.0f;
        mn8[j] = 3.402823466e+38f; mx8[j] = -3.402823466e+38f;
      }
      auto acc8 = [&](bf8_t hv, unsigned int aa) {
        union { bf8_t v; unsigned int u[4]; } cv; cv.v = hv;
        const float* ep = &et_s[aa * 384 + c0];
        f4_t ea = *(const f4_t*)ep;
        f4_t eb = *(const f4_t*)(ep + 4);
        float vv[8], ee[8];
        #pragma unroll
        for (int j = 0; j < 4; ++j) {
          vv[2 * j] = bflo(cv.u[j]); vv[2 * j + 1] = bfhi(cv.u[j]);
          ee[j] = ea[j]; ee[4 + j] = eb[j];
        }
        #pragma unroll
        for (int j = 0; j < 8; ++j) {
          float q = vv[j] + ee[j];
          s8[j] += q;
          q8[j] = fmaf(q, q, q8[j]);
          mn8[j] = fminf(mn8[j], q);
          mx8[j] = fmaxf(mx8[j], q);
        }
      };
      for (int e = e0; e < e1; ) {
        int m = e1 - e;
        unsigned int pk0 = cpack[e];
        unsigned int pk1 = cpack[m > 1 ? e + 1 : e];
        unsigned int pk2 = cpack[m > 2 ? e + 2 : e];
        unsigned int pk3 = cpack[m > 3 ? e + 3 : e];
        bf8_t h0 = *((const bf8_t*)(Hsrc + (size_t)(pk0 & 0xFFFFu) * 384) + lane);
        bf8_t h1 = *((const bf8_t*)(Hsrc + (size_t)(pk1 & 0xFFFFu) * 384) + lane);
        bf8_t h2 = *((const bf8_t*)(Hsrc + (size_t)(pk2 & 0xFFFFu) * 384) + lane);
        bf8_t h3 = *((const bf8_t*)(Hsrc + (size_t)(pk3 & 0xFFFFu) * 384) + lane);
        acc8(h0, pk0 >> 16);
        if (m > 1) acc8(h1, pk1 >> 16);
        if (m > 2) acc8(h2, pk2 >> 16);
        if (m > 3) acc8(h3, pk3 >> 16);
        e += (m < 4) ? m : 4;
      }
      // finalize
      int d = e1 - e0;
      float inv = (d > 0) ? (1.0f / (float)d) : 0.0f;
      f4_t cda = *(const f4_t*)&Cd_s[w * 384 + c0];
      f4_t cdb = *(const f4_t*)&Cd_s[w * 384 + c0 + 4];
      #pragma unroll
      for (int j = 0; j < 8; ++j) {
        int c = c0 + j;
        if (c < 375) {
          float cd = (j < 4) ? cda[j] : cdb[j - 4];
          float mean, mnv, mxv, sd;
          if (d > 0) {
            float mu = s8[j] * inv;
            mean = cd + mu;
            mnv = cd + mn8[j];
            mxv = cd + mx8[j];
            sd = sqrtf(fmaxf(q8[j] * inv - mu * mu, 0.0f) + 1e-5f);
          } else { mean = 0.0f; mnv = 0.0f; mxv = 0.0f; sd = 0.0031622776601683794f; }
          int t = c / 75, f = c - (c / 75) * 75;
          uint2 pkv;
          pkv.x = (unsigned int)f2bf(mean) | ((unsigned int)f2bf(mnv) << 16);
          pkv.y = (unsigned int)f2bf(mxv) | ((unsigned int)f2bf(sd) << 16);
          *(uint2*)&A_s[w * 1608 + t * 320 + f * 4] = pkv;
        }
      }
    }
  }
  __syncthreads();

  // ---- per-tower MFMA: [8(16) nodes x 320] @ [320 x 16 cols], 15 tasks over 8 waves ----
  f4_t accs[2];
  #pragma unroll
  for (int r = 0; r < 2; ++r) {
    int task = w + r * 8;
    f4_t acc = {0.f, 0.f, 0.f, 0.f};
    if (task < 15) {
      int t = task % 5, nf = task / 5;
      const unsigned short* ap = &A_s[(l15 & 7) * 1608 + t * 320 + l4 * 8];
      const unsigned short* wp = WcombT_l + (size_t)(t * 48 + nf * 16 + l15) * 320 + l4 * 8;
      #pragma unroll
      for (int ks = 0; ks < 10; ++ks) {
        bf8_t av = *(const bf8_t*)(ap + ks * 32);
        bf8_t bv = *(const bf8_t*)(wp + ks * 32);
        acc = __builtin_amdgcn_mfma_f32_16x16x32_bf16(av, bv, acc, 0, 0, 0);
      }
    }
    accs[r] = acc;
  }
  __syncthreads();   // all A_s reads done -> safe to alias

  float* Out = (float*)A_s;   // f32 [8][256]
  #pragma unroll
  for (int r = 0; r < 2; ++r) {
    int task = w + r * 8;
    if (task < 15) {
      int t = task % 5, nf = task / 5;
      #pragma unroll
      for (int i = 0; i < 4; ++i) {
        int row = l4 * 4 + i;
        if (row < 8) Out[row * 256 + t * 48 + nf * 16 + l15] = accs[r][i];
      }
    }
  }
  __syncthreads();

  // ---- scaler combine -> Cb bf16 [8][104] ----
  unsigned short* Cb = (unsigned short*)((char*)A_s + 8192);
  for (int item = tid; item < 8 * 104; item += 512) {
    int n = item / 104, o = item - (item / 104) * 104;
    unsigned short v = 0;
    if (o < 75) {
      int t = o / 15, jj = o - (o / 15) * 15;
      int g = n0 + n;
      const float* ob = Out + n * 256 + t * 48;
      float cv = ob[jj] + amp[g] * ob[15 + jj] + invamp[g] * ob[30 + jj];
      v = f2bf(cv);
    }
    Cb[n * 104 + o] = v;
  }
  __syncthreads();

  // ---- lin GEMM: Z = Cb @ Wlin + Xp + zb ----
  if (w < 5) {
    int cc = w * 16 + l15;
    f4_t acc = {0.f, 0.f, 0.f, 0.f};
    const unsigned short* ap2 = Cb + (l15 & 7) * 104;
    const unsigned short* bp2 = WlinT_l + (size_t)cc * 96;
    #pragma unroll
    for (int ks = 0; ks < 3; ++ks) {
      bf8_t av = *(const bf8_t*)(ap2 + ks * 32 + l4 * 8);
      bf8_t bv = *(const bf8_t*)(bp2 + ks * 32 + l4 * 8);
      acc = __builtin_amdgcn_mfma_f32_16x16x32_bf16(av, bv, acc, 0, 0, 0);
    }
    if (cc < 75) {
      #pragma unroll
      for (int i = 0; i < 4; ++i) {
        int row = l4 * 4 + i;
        if (row < 8) {
          int g = n0 + row;
          Z[(size_t)g * 75 + cc] = acc[i] + Xp_s[row * 80 + cc] + zb_l[cc];
        }
      }
    }
  }
}

// ---------------- batchnorm ----------------
#define BN_BLOCKS 256
#define BN_ROWS 196
__global__ __launch_bounds__(256) void k_bnstats(const float* __restrict__ Z, float* __restrict__ partial) {
  __shared__ float sArr[225];
  __shared__ float qArr[225];
  int tid = threadIdx.x;
  int r0 = blockIdx.x * BN_ROWS;
  int r1 = r0 + BN_ROWS; if (r1 > NN) r1 = NN;
  float s = 0.0f, q = 0.0f;
  if (tid < 225) {
    int rr = tid / 75, c = tid - rr * 75;
    for (int r = r0 + rr; r < r1; r += 3) {
      float v = Z[(size_t)r * 75 + c];
      s += v; q += v * v;
    }
    sArr[tid] = s; qArr[tid] = q;
  }
  __syncthreads();
  if (tid < 75) {
    float S = sArr[tid] + sArr[75 + tid] + sArr[150 + tid];
    float Q = qArr[tid] + qArr[75 + tid] + qArr[150 + tid];
    partial[blockIdx.x * 150 + tid] = S;
    partial[blockIdx.x * 150 + 75 + tid] = Q;
  }
}

__global__ void k_bnfinal(const float* __restrict__ partial, float* __restrict__ musig) {
  int c = threadIdx.x;
  if (c < 75) {
    float S = 0.0f, Q = 0.0f;
    for (int b = 0; b < BN_BLOCKS; ++b) { S += partial[b * 150 + c]; Q += partial[b * 150 + 75 + c]; }
    float mu = S * (1.0f / NN);
    float var = fmaxf(Q * (1.0f / NN) - mu * mu, 0.0f);
    musig[c] = mu;
    musig[75 + c] = 1.0f / sqrtf(var + 1e-5f);
  }
}

// BN apply + relu. layers 0-2: write hbf only; last layer: write hf32 only (for pooling).
__global__ void k_bnapply(const float* __restrict__ Z, const float* __restrict__ musig,
                          const float* __restrict__ gamma_l, const float* __restrict__ beta_l,
                          unsigned short* __restrict__ hbf, float* __restrict__ hf32, int last) {
  int i = blockIdx.x * 256 + threadIdx.x;
  if (i < NN * 96) {
    int n = i / 96, c = i - (i / 96) * 96;
    if (c < 75) {
      float v = (Z[(size_t)n * 75 + c] - musig[c]) * musig[75 + c];
      v = fmaxf(gamma_l[c] * v + beta_l[c], 0.0f);
      if (last) hf32[(size_t)n * 75 + c] = v;
      else hbf[i] = f2bf(v);
    } else if (!last) {
      hbf[i] = 0;
    }
  }
}

// ---------------- pool + MLP head ----------------
__global__ __launch_bounds__(128) void k_pool_mlp(const float* __restrict__ h, const int* __restrict__ batch,
                                                  const float* __restrict__ W1, const float* __restrict__ b1,
                                                  const float* __restrict__ W2, const float* __restrict__ b2,
                                                  const float* __restrict__ W3, const float* __restrict__ b3,
                                                  float* __restrict__ out) {
  __shared__ float pooled[75];
  __shared__ float z1[50];
  __shared__ float z2[25];
  __shared__ int se[2];
  int g = blockIdx.x, tid = threadIdx.x;
  if (tid < 2) {
    int target = g + tid;
    int lo = 0, hi = NN;
    while (lo < hi) { int mid = (lo + hi) >> 1; if (batch[mid] < target) lo = mid + 1; else hi = mid; }
    se[tid] = lo;
  }
  __syncthreads();
  int s = se[0], e = se[1];
  if (tid < 75) {
    float acc = 0.0f;
    for (int r = s; r < e; ++r) acc += h[(size_t)r * 75 + tid];
    pooled[tid] = acc;
  }
  __syncthreads();
  if (tid < 50) {
    float acc = b1[tid];
    for (int c = 0; c < 75; ++c) acc += pooled[c] * W1[c * 50 + tid];
    z1[tid] = fmaxf(acc, 0.0f);
  }
  __syncthreads();
  if (tid < 25) {
    float acc = b2[tid];
    for (int c = 0; c < 50; ++c) acc += z1[c] * W2[c * 25 + tid];
    z2[tid] = fmaxf(acc, 0.0f);
  }
  __syncthreads();
  if (tid == 0) {
    float acc = b3[0];
    for (int c = 0; c < 25; ++c) acc += z2[c] * W3[c];
    out[g] = acc;
  }
}

// ---------------- launch ----------------
extern "C" void kernel_launch(void* const* d_in, const int* in_sizes, int n_in,
                              void* d_out, int out_size, void* d_ws, size_t ws_size,
                              hipStream_t stream) {
  const int* x = (const int*)d_in[0];
  const int* ei = (const int*)d_in[1];
  const int* eattr = (const int*)d_in[2];
  const int* batch = (const int*)d_in[3];
  const float* node_emb = (const float*)d_in[4];
  const float* edge_emb = (const float*)d_in[5];
  const float* We = (const float*)d_in[6];
  const float* be = (const float*)d_in[7];
  const float* Wpre = (const float*)d_in[8];
  const float* bpre = (const float*)d_in[9];
  const float* Wpost = (const float*)d_in[10];
  const float* bpost = (const float*)d_in[11];
  const float* Wlin = (const float*)d_in[12];
  const float* blin = (const float*)d_in[13];
  const float* gamma = (const float*)d_in[14];
  const float* beta = (const float*)d_in[15];
  const float* W1 = (const float*)d_in[16];
  const float* b1 = (const float*)d_in[17];
  const float* W2 = (const float*)d_in[18];
  const float* b2 = (const float*)d_in[19];
  const float* W3 = (const float*)d_in[20];
  const float* b3 = (const float*)d_in[21];
  float* out = (float*)d_out;

  const int* src = ei;
  const int* dst = ei + NE;

  char* p = (char*)d_ws;
  auto alloc = [&](size_t bytes) { char* r = p; p += (bytes + 255) & ~(size_t)255; return r; };
  int* deg     = (int*)alloc((size_t)NN * 4);
  int* off     = (int*)alloc((size_t)(NN + 1) * 4);
  int* cursor  = (int*)alloc((size_t)NN * 4);
  unsigned int* cpack = (unsigned int*)alloc((size_t)NE * 4);
  float* amp    = (float*)alloc((size_t)NN * 4);
  float* invamp = (float*)alloc((size_t)NN * 4);
  unsigned short* hbf  = (unsigned short*)alloc((size_t)NN * 96 * 2);
  float* hf32          = (float*)alloc((size_t)NN * 75 * 4);
  unsigned short* Hsrc = (unsigned short*)alloc((size_t)NN * 384 * 2 + 256);
  float* Z             = (float*)alloc((size_t)NN * 75 * 4 + 256);
  unsigned short* B1Ts   = (unsigned short*)alloc((size_t)4 * 384 * 96 * 2);
  unsigned short* B1Td   = (unsigned short*)alloc((size_t)4 * 384 * 96 * 2);
  unsigned short* WXT    = (unsigned short*)alloc((size_t)4 * 80 * 96 * 2);
  unsigned short* WlinT  = (unsigned short*)alloc((size_t)4 * 80 * 96 * 2);
  unsigned short* WcombT = (unsigned short*)alloc((size_t)4 * 5 * 48 * 320 * 2);
  float* WXlin = (float*)alloc((size_t)4 * 5625 * 4);
  float* zb    = (float*)alloc((size_t)4 * 75 * 4);
  float* etab  = (float*)alloc((size_t)4 * 4 * 384 * 4);
  float* bnpart = (float*)alloc((size_t)BN_BLOCKS * 150 * 4);
  float* musig  = (float*)alloc((size_t)150 * 4);

  hipMemsetAsync(deg, 0, (size_t)NN * 4, stream);
  k_deg<<<(NE + 255) / 256, 256, 0, stream>>>(dst, deg);
  k_scan<<<1, 1024, 0, stream>>>(deg, off);
  k_amp<<<(NN + 255) / 256, 256, 0, stream>>>(deg, off, amp, invamp, cursor);
  k_fill<<<(NE + 255) / 256, 256, 0, stream>>>(src, dst, eattr, cursor, cpack);
  k_embed<<<(NN * 96 + 255) / 256, 256, 0, stream>>>(x, node_emb, hbf);
  k_wxlin<<<4, 256, 0, stream>>>(Wpost, Wlin, WXlin);
  k_zb<<<4, 128, 0, stream>>>(bpost, blin, Wlin, zb);
  {
    int tot = 4 * 384 * 96 * 2 + 4 * 80 * 96 * 2;
    k_packAll<<<(tot + 255) / 256, 256, 0, stream>>>(Wpre, WXlin, Wlin, B1Ts, B1Td, WXT, WlinT);
  }
  k_packWcomb<<<(4 * 5 * 48 * 320 + 255) / 256, 256, 0, stream>>>(Wpost, WcombT);
  k_etab<<<16, 256, 0, stream>>>(edge_emb, We, be, Wpre, etab);

  for (int l = 0; l < NL; ++l) {
    k_gemm1<<<(NN + 63) / 64, 256, 0, stream>>>(hbf, B1Ts + (size_t)l * 384 * 96, Hsrc);
    k_agg<<<NN / 8, 512, 0, stream>>>(hbf, Hsrc, off, cpack,
                                      etab + (size_t)l * 4 * 384,
                                      B1Td + (size_t)l * 384 * 96,
                                      bpre + l * 375,
                                      WXT + (size_t)l * 80 * 96,
                                      WcombT + (size_t)l * 5 * 48 * 320,
                                      WlinT + (size_t)l * 80 * 96,
                                      amp, invamp, zb + l * 75, Z);
    k_bnstats<<<BN_BLOCKS, 256, 0, stream>>>(Z, bnpart);
    k_bnfinal<<<1, 128, 0, stream>>>(bnpart, musig);
    k_bnapply<<<(NN * 96 + 255) / 256, 256, 0, stream>>>(Z, musig, gamma + l * 75, beta + l * 75, hbf, hf32, l == NL - 1);
  }
  k_pool_mlp<<<NG, 128, 0, stream>>>(hf32, batch, W1, b1, W2, b2, W3, b3, out);
}